// Round 1
// baseline (325.119 us; speedup 1.0000x reference)
//
#include <hip/hip_runtime.h>
#include <hip/hip_bf16.h>

#define TSEQ 2048
#define HID 384
#define NHEAD 4
#define HD 96
#define NBATCH 8

using bf16 = __bf16;
typedef bf16 bf16x8 __attribute__((ext_vector_type(8)));
typedef bf16 bf16x4 __attribute__((ext_vector_type(4)));
typedef float f32x4 __attribute__((ext_vector_type(4)));

static __device__ __forceinline__ f32x4 mfma16(bf16x8 a, bf16x8 b, f32x4 c) {
    return __builtin_amdgcn_mfma_f32_16x16x32_bf16(a, b, c, 0, 0, 0);
}

// ---------------- conversion kernels ----------------
__global__ void k_conv8(const float* __restrict__ src, bf16* __restrict__ dst, int n8) {
    int t = blockIdx.x * 256 + threadIdx.x;
    if (t >= n8) return;
    const float4* s4 = reinterpret_cast<const float4*>(src);
    float4 a = s4[2 * t], b = s4[2 * t + 1];
    bf16x8 o;
    o[0] = (bf16)a.x; o[1] = (bf16)a.y; o[2] = (bf16)a.z; o[3] = (bf16)a.w;
    o[4] = (bf16)b.x; o[5] = (bf16)b.y; o[6] = (bf16)b.z; o[7] = (bf16)b.w;
    *reinterpret_cast<bf16x8*>(dst + 8 * t) = o;
}

__global__ void k_convT(const float* __restrict__ W, bf16* __restrict__ WT) {
    int t = blockIdx.x * 256 + threadIdx.x;  // 147456 threads: WT[n][k] = W[k][n]
    int n = t / HID, k = t % HID;
    WT[t] = (bf16)W[(size_t)k * HID + n];
}

// ---------------- projection GEMM (Q,K,V,pos) ----------------
// C[m][n] = A[m][:] . WT[n][:]   (A bf16 [M][384], WT bf16 [384][384])
__launch_bounds__(256, 2)
__global__ void k_proj(const bf16* __restrict__ X, const bf16* __restrict__ P,
                       const bf16* __restrict__ wqT, const bf16* __restrict__ wkT,
                       const bf16* __restrict__ wvT, const bf16* __restrict__ wpT,
                       const float* __restrict__ bq, const float* __restrict__ bk,
                       const float* __restrict__ bv,
                       const float* __restrict__ pbu, const float* __restrict__ pbv,
                       bf16* __restrict__ qu, bf16* __restrict__ qv,
                       bf16* __restrict__ kws, bf16* __restrict__ vt,
                       bf16* __restrict__ pp) {
    __shared__ bf16 wt_lds[96][392];  // padded stride (784B) -> ~2-way conflicts
    int mat = blockIdx.z;             // 0=Q 1=K 2=V 3=POS
    int m0 = blockIdx.x * 64;
    if (mat == 3 && m0 >= 4095) return;
    int n0 = blockIdx.y * 96;
    const bf16* A  = (mat == 3) ? P : X;
    const bf16* WT = (mat == 0) ? wqT : (mat == 1) ? wkT : (mat == 2) ? wvT : wpT;
    int tid = threadIdx.x;
    #pragma unroll
    for (int s = 0; s < 18; ++s) {
        int cc = tid + 256 * s;         // 96 rows x 48 chunks of 8 bf16
        int r = cc / 48, ch = cc % 48;
        *reinterpret_cast<int4*>(&wt_lds[r][ch * 8]) =
            *reinterpret_cast<const int4*>(WT + (size_t)(n0 + r) * HID + ch * 8);
    }
    __syncthreads();
    int lane = tid & 63, w = tid >> 6;
    int c = lane & 15, g = lane >> 4;
    int arow = m0 + 16 * w + c;
    if (mat == 3 && arow > 4095) arow = 4095;  // clamped, stores guarded below
    const bf16* Abase = A + (size_t)arow * HID + 8 * g;
    f32x4 acc[6] = {};
    for (int ks = 0; ks < 12; ++ks) {
        bf16x8 a = *reinterpret_cast<const bf16x8*>(Abase + 32 * ks);
        #pragma unroll
        for (int jt = 0; jt < 6; ++jt) {
            bf16x8 b = *reinterpret_cast<const bf16x8*>(&wt_lds[16 * jt + c][32 * ks + 8 * g]);
            acc[jt] = mfma16(a, b, acc[jt]);
        }
    }
    int h = blockIdx.y;  // n0 = 96*h -> this block's 96 cols == one head
    int rbase = m0 + 16 * w + 4 * g;
    if (mat == 0) {
        #pragma unroll
        for (int jt = 0; jt < 6; ++jt) {
            int n = n0 + 16 * jt + c;
            int d = 16 * jt + c;
            float bb = bq[n], bu = pbu[n], bvv = pbv[n];
            #pragma unroll
            for (int j = 0; j < 4; ++j) {
                int m = rbase + j;
                int b_ = m >> 11, t = m & 2047;
                size_t o = (((size_t)(b_ * NHEAD + h)) * TSEQ + t) * HD + d;
                float q = acc[jt][j] + bb;
                qu[o] = (bf16)(q + bu);
                qv[o] = (bf16)(q + bvv);
            }
        }
    } else if (mat == 1) {
        #pragma unroll
        for (int jt = 0; jt < 6; ++jt) {
            int n = n0 + 16 * jt + c;
            int d = 16 * jt + c;
            float bb = bk[n];
            #pragma unroll
            for (int j = 0; j < 4; ++j) {
                int m = rbase + j;
                int b_ = m >> 11, t = m & 2047;
                size_t o = (((size_t)(b_ * NHEAD + h)) * TSEQ + t) * HD + d;
                kws[o] = (bf16)(acc[jt][j] + bb);
            }
        }
    } else if (mat == 2) {
        // V stored transposed: vt[(bh*96 + d)*T + t]; 4 consecutive t -> 8B store
        #pragma unroll
        for (int jt = 0; jt < 6; ++jt) {
            int n = n0 + 16 * jt + c;
            int d = 16 * jt + c;
            float bb = bv[n];
            int m = rbase;
            int b_ = m >> 11, t0 = m & 2047;
            size_t o = (((size_t)(b_ * NHEAD + h)) * HD + d) * TSEQ + t0;
            bf16x4 pk;
            #pragma unroll
            for (int j = 0; j < 4; ++j) pk[j] = (bf16)(acc[jt][j] + bb);
            *reinterpret_cast<bf16x4*>(vt + o) = pk;
        }
    } else {
        #pragma unroll
        for (int jt = 0; jt < 6; ++jt) {
            int d = 16 * jt + c;
            #pragma unroll
            for (int j = 0; j < 4; ++j) {
                int m = rbase + j;
                if (m < 4095) {
                    size_t o = ((size_t)h * 4096 + m) * HD + d;
                    pp[o] = (bf16)acc[jt][j];
                }
            }
        }
    }
}

// ---------------- fused rel-pos flash attention ----------------
// grid (T/64, B*H), 256 threads = 4 waves, each wave owns 16 q-rows.
__launch_bounds__(256, 2)
__global__ void k_attn(const bf16* __restrict__ qu, const bf16* __restrict__ qv,
                       const bf16* __restrict__ kws, const bf16* __restrict__ vt,
                       const bf16* __restrict__ pp, const int* __restrict__ mask,
                       bf16* __restrict__ out) {
    __shared__ bf16 k_lds[64][104];       // K tile, padded rows
    __shared__ bf16 pos_lds[128][104];    // pos band, padded rows
    __shared__ bf16 vt_lds[96][64];       // V^T tile, XOR-swizzled 16B chunks
    __shared__ bf16 win_lds[4][16][84];   // per-wave rel-pos window scores
    __shared__ bf16 p_lds[4][16][72];     // per-wave P for PV A-frags
    __shared__ float msk_lds[64];

    int q0 = blockIdx.x * 64;
    int bh = blockIdx.y;
    int b_ = bh >> 2;
    int h  = bh & 3;
    int tid = threadIdx.x, lane = tid & 63, w = tid >> 6;
    int c = lane & 15, g = lane >> 4;

    // Q fragments held in registers for the whole kernel
    bf16x8 qu_f[3], qv_f[3];
    {
        size_t rowbase = ((size_t)bh * TSEQ + q0 + 16 * w + c) * HD + 8 * g;
        #pragma unroll
        for (int ds = 0; ds < 3; ++ds) {
            qu_f[ds] = *reinterpret_cast<const bf16x8*>(qu + rowbase + 32 * ds);
            qv_f[ds] = *reinterpret_cast<const bf16x8*>(qv + rowbase + 32 * ds);
        }
    }

    f32x4 acc_o[6] = {};
    float mrow[4], lrow[4];
    #pragma unroll
    for (int j = 0; j < 4; ++j) { mrow[j] = -3.0e38f; lrow[j] = 0.f; }

    const float SCALE = 0.10206207262f;   // 1/sqrt(96)
    const float L2E   = 1.44269504089f;
    int sw = 48 - 16 * w;                 // wave's window start col (abs)

    for (int kt = 0; kt < TSEQ / 64; ++kt) {
        int k0 = kt * 64;
        __syncthreads();  // previous tile's compute done before overwrite

        {   // stage K: 64 rows x 12 chunks
            const bf16* kbase = kws + ((size_t)bh * TSEQ + k0) * HD;
            #pragma unroll
            for (int s = 0; s < 3; ++s) {
                int cc = tid + 256 * s;
                int r = cc / 12, ch = cc % 12;
                *reinterpret_cast<int4*>(&k_lds[r][ch * 8]) =
                    *reinterpret_cast<const int4*>(kbase + (size_t)r * HD + ch * 8);
            }
        }
        {   // stage V^T with chunk XOR swizzle: 96 rows x 8 chunks
            const bf16* vbase = vt + (size_t)bh * HD * TSEQ + k0;
            #pragma unroll
            for (int s = 0; s < 3; ++s) {
                int cc = tid + 256 * s;
                int r = cc >> 3, ch = cc & 7;
                int4 v = *reinterpret_cast<const int4*>(vbase + (size_t)r * TSEQ + ch * 8);
                *reinterpret_cast<int4*>(&vt_lds[r][((ch ^ (r & 7)) * 8)]) = v;
            }
        }
        {   // stage pos band: rows n_base..n_base+127 (always in [0,4095])
            int n_base = TSEQ - 1 + k0 - q0 - 63;
            const bf16* pbase = pp + ((size_t)h * 4096 + n_base) * HD;
            #pragma unroll
            for (int s = 0; s < 6; ++s) {
                int cc = tid + 256 * s;
                int r = cc / 12, ch = cc % 12;
                *reinterpret_cast<int4*>(&pos_lds[r][ch * 8]) =
                    *reinterpret_cast<const int4*>(pbase + (size_t)r * HD + ch * 8);
            }
        }
        if (tid < 64) msk_lds[tid] = (mask[b_ * TSEQ + k0 + tid] == 0) ? -1e30f : 0.f;
        __syncthreads();

        // content scores: q_u . K^T  -> 4 tiles of 16x16
        f32x4 acc_ac[4] = {};
        #pragma unroll
        for (int ds = 0; ds < 3; ++ds) {
            #pragma unroll
            for (int t = 0; t < 4; ++t) {
                bf16x8 bfr = *reinterpret_cast<const bf16x8*>(&k_lds[16 * t + c][32 * ds + 8 * g]);
                acc_ac[t] = mfma16(qu_f[ds], bfr, acc_ac[t]);
            }
        }
        // rel-pos window: q_v . pos_band^T -> 5 tiles covering this wave's 79 cols
        f32x4 acc_w[5] = {};
        #pragma unroll
        for (int ds = 0; ds < 3; ++ds) {
            #pragma unroll
            for (int t = 0; t < 5; ++t) {
                bf16x8 bfr = *reinterpret_cast<const bf16x8*>(&pos_lds[sw + 16 * t + c][32 * ds + 8 * g]);
                acc_w[t] = mfma16(qv_f[ds], bfr, acc_w[t]);
            }
        }
        // spill window scores (per-wave) for diagonal gather
        #pragma unroll
        for (int t = 0; t < 5; ++t) {
            #pragma unroll
            for (int j = 0; j < 4; ++j)
                win_lds[w][4 * g + j][16 * t + c] = (bf16)acc_w[t][j];
        }
        __threadfence_block();  // same-wave cross-lane LDS handoff

        // assemble scores + online softmax (rows r=4g+j, cols across 16 c-lanes)
        float sArr[4][4];
        #pragma unroll
        for (int t = 0; t < 4; ++t) {
            float ma = msk_lds[16 * t + c];
            #pragma unroll
            for (int j = 0; j < 4; ++j) {
                int r = 4 * g + j;
                float wv = (float)win_lds[w][r][16 * t + c - r + 15];  // bd[q][k]
                sArr[t][j] = (acc_ac[t][j] + wv) * SCALE + ma;
            }
        }
        #pragma unroll
        for (int j = 0; j < 4; ++j) {
            float rm = fmaxf(fmaxf(sArr[0][j], sArr[1][j]), fmaxf(sArr[2][j], sArr[3][j]));
            rm = fmaxf(rm, __shfl_xor(rm, 1));
            rm = fmaxf(rm, __shfl_xor(rm, 2));
            rm = fmaxf(rm, __shfl_xor(rm, 4));
            rm = fmaxf(rm, __shfl_xor(rm, 8));
            float mnew = fmaxf(mrow[j], rm);
            float alpha = exp2f((mrow[j] - mnew) * L2E);
            mrow[j] = mnew;
            float rs = 0.f;
            #pragma unroll
            for (int t = 0; t < 4; ++t) {
                float pv = exp2f((sArr[t][j] - mnew) * L2E);
                sArr[t][j] = pv;
                rs += pv;
            }
            rs += __shfl_xor(rs, 1);
            rs += __shfl_xor(rs, 2);
            rs += __shfl_xor(rs, 4);
            rs += __shfl_xor(rs, 8);
            lrow[j] = lrow[j] * alpha + rs;
            #pragma unroll
            for (int ot = 0; ot < 6; ++ot) acc_o[ot][j] *= alpha;
        }
        // P -> LDS (bf16) for PV A-frags
        #pragma unroll
        for (int t = 0; t < 4; ++t) {
            #pragma unroll
            for (int j = 0; j < 4; ++j)
                p_lds[w][4 * g + j][16 * t + c] = (bf16)sArr[t][j];
        }
        __threadfence_block();
        // PV: O += P . V
        #pragma unroll
        for (int kk2 = 0; kk2 < 2; ++kk2) {
            bf16x8 pa = *reinterpret_cast<const bf16x8*>(&p_lds[w][c][32 * kk2 + 8 * g]);
            #pragma unroll
            for (int ot = 0; ot < 6; ++ot) {
                int rr = 16 * ot + c;
                bf16x8 bfr = *reinterpret_cast<const bf16x8*>(
                    &vt_lds[rr][((4 * kk2 + g) ^ (rr & 7)) * 8]);
                acc_o[ot] = mfma16(pa, bfr, acc_o[ot]);
            }
        }
    }

    // epilogue: normalize, store attn output as [B*T][384] bf16
    int rbase = q0 + 16 * w + 4 * g;
    #pragma unroll
    for (int j = 0; j < 4; ++j) {
        float inv = 1.0f / lrow[j];
        size_t m = (size_t)b_ * TSEQ + rbase + j;
        #pragma unroll
        for (int ot = 0; ot < 6; ++ot)
            out[m * HID + h * HD + 16 * ot + c] = (bf16)(acc_o[ot][j] * inv);
    }
}

// ---------------- output projection (fp32 out + bias) ----------------
__launch_bounds__(256, 2)
__global__ void k_oproj(const bf16* __restrict__ A, const bf16* __restrict__ WT,
                        const float* __restrict__ bias, float* __restrict__ out) {
    __shared__ bf16 wt_lds[96][392];
    int m0 = blockIdx.x * 64, n0 = blockIdx.y * 96;
    int tid = threadIdx.x;
    #pragma unroll
    for (int s = 0; s < 18; ++s) {
        int cc = tid + 256 * s;
        int r = cc / 48, ch = cc % 48;
        *reinterpret_cast<int4*>(&wt_lds[r][ch * 8]) =
            *reinterpret_cast<const int4*>(WT + (size_t)(n0 + r) * HID + ch * 8);
    }
    __syncthreads();
    int lane = tid & 63, w = tid >> 6;
    int c = lane & 15, g = lane >> 4;
    const bf16* Abase = A + (size_t)(m0 + 16 * w + c) * HID + 8 * g;
    f32x4 acc[6] = {};
    for (int ks = 0; ks < 12; ++ks) {
        bf16x8 a = *reinterpret_cast<const bf16x8*>(Abase + 32 * ks);
        #pragma unroll
        for (int jt = 0; jt < 6; ++jt) {
            bf16x8 b = *reinterpret_cast<const bf16x8*>(&wt_lds[16 * jt + c][32 * ks + 8 * g]);
            acc[jt] = mfma16(a, b, acc[jt]);
        }
    }
    int rbase = m0 + 16 * w + 4 * g;
    #pragma unroll
    for (int jt = 0; jt < 6; ++jt) {
        int n = n0 + 16 * jt + c;
        float bb = bias[n];
        #pragma unroll
        for (int j = 0; j < 4; ++j)
            out[(size_t)(rbase + j) * HID + n] = acc[jt][j] + bb;
    }
}

extern "C" void kernel_launch(void* const* d_in, const int* in_sizes, int n_in,
                              void* d_out, int out_size, void* d_ws, size_t ws_size,
                              hipStream_t stream) {
    const float* hs  = (const float*)d_in[0];
    const float* pe  = (const float*)d_in[1];
    const int*   msk = (const int*)d_in[2];
    const float* Wq  = (const float*)d_in[3];
    const float* bq  = (const float*)d_in[4];
    const float* Wk  = (const float*)d_in[5];
    const float* bk  = (const float*)d_in[6];
    const float* Wv  = (const float*)d_in[7];
    const float* bv  = (const float*)d_in[8];
    const float* Wo  = (const float*)d_in[9];
    const float* bo  = (const float*)d_in[10];
    const float* Wp  = (const float*)d_in[11];
    const float* pbu = (const float*)d_in[12];
    const float* pbv = (const float*)d_in[13];

    char* ws = (char*)d_ws;
    size_t off = 0;
    auto alloc = [&](size_t b) { char* p = ws + off; off += (b + 255) & ~(size_t)255; return p; };
    bf16* Xb  = (bf16*)alloc((size_t)16384 * HID * 2);
    bf16* Pb  = (bf16*)alloc((size_t)4096 * HID * 2);
    bf16* wqT = (bf16*)alloc((size_t)HID * HID * 2);
    bf16* wkT = (bf16*)alloc((size_t)HID * HID * 2);
    bf16* wvT = (bf16*)alloc((size_t)HID * HID * 2);
    bf16* woT = (bf16*)alloc((size_t)HID * HID * 2);
    bf16* wpT = (bf16*)alloc((size_t)HID * HID * 2);
    bf16* qu  = (bf16*)alloc((size_t)NBATCH * NHEAD * TSEQ * HD * 2);
    bf16* qv  = (bf16*)alloc((size_t)NBATCH * NHEAD * TSEQ * HD * 2);
    bf16* kws = (bf16*)alloc((size_t)NBATCH * NHEAD * TSEQ * HD * 2);
    bf16* vt  = (bf16*)alloc((size_t)NBATCH * NHEAD * TSEQ * HD * 2);
    bf16* pp  = (bf16*)alloc((size_t)NHEAD * 4096 * HD * 2);
    bf16* ao  = (bf16*)alloc((size_t)16384 * HID * 2);

    k_conv8<<<3072, 256, 0, stream>>>(hs, Xb, 786432);       // 16384*384/8
    k_conv8<<<768, 256, 0, stream>>>(pe, Pb, 196560);        // 4095*384/8
    k_convT<<<576, 256, 0, stream>>>(Wq, wqT);
    k_convT<<<576, 256, 0, stream>>>(Wk, wkT);
    k_convT<<<576, 256, 0, stream>>>(Wv, wvT);
    k_convT<<<576, 256, 0, stream>>>(Wo, woT);
    k_convT<<<576, 256, 0, stream>>>(Wp, wpT);
    k_proj<<<dim3(256, 4, 4), 256, 0, stream>>>(Xb, Pb, wqT, wkT, wvT, wpT,
                                                bq, bk, bv, pbu, pbv,
                                                qu, qv, kws, vt, pp);
    k_attn<<<dim3(32, 32), 256, 0, stream>>>(qu, qv, kws, vt, pp, msk, ao);
    k_oproj<<<dim3(256, 4), 256, 0, stream>>>(ao, woT, bo, (float*)d_out);
}